// Round 9
// baseline (389.407 us; speedup 1.0000x reference)
//
#include <hip/hip_runtime.h>
#include <hip/hip_bf16.h>
#include <cstdint>

#define B_   8
#define L_   1024
#define F_   1024
#define H_   256
#define NH_  8
#define LBL_ 4766
#define M_   (B_*L_)    // 8192
#define OD_  (NH_*H_)   // 2048
#define NCM  (LBL_*LBL_)     // 22714756
#define MP_EPB 16384
#define MP_NB  ((NCM + MP_EPB - 1) / MP_EPB)   // 1387

typedef unsigned short u16;
typedef unsigned int   u32;
typedef __attribute__((ext_vector_type(8))) short short8;
typedef __attribute__((ext_vector_type(4))) float float4v;

#define BF16_ONES_PAIR 0x3f803f80u

__device__ __forceinline__ float bf2f(u32 u) { return __uint_as_float(u << 16); }
__device__ __forceinline__ u16 f2bf(float f) {
    u32 u = __float_as_uint(f);
    u32 r = 0x7fffu + ((u >> 16) & 1u);
    return (u16)((u + r) >> 16);
}

struct f8 { float v[8]; };

__device__ __forceinline__ float ldS(const void* p, size_t i, bool bf) {
    return bf ? bf2f(((const u16*)p)[i]) : ((const float*)p)[i];
}
__device__ __forceinline__ float4 ld4(const void* p, size_t i, bool bf) {
    if (bf) {
        uint2 u = *(const uint2*)((const u16*)p + i);
        return make_float4(bf2f(u.x & 0xffff), bf2f(u.x >> 16),
                           bf2f(u.y & 0xffff), bf2f(u.y >> 16));
    }
    return *(const float4*)((const float*)p + i);
}
__device__ __forceinline__ f8 ld8(const void* p, size_t i, bool bf) {
    f8 r;
    if (bf) {
        uint4 u = *(const uint4*)((const u16*)p + i);
        r.v[0]=bf2f(u.x&0xffff); r.v[1]=bf2f(u.x>>16);
        r.v[2]=bf2f(u.y&0xffff); r.v[3]=bf2f(u.y>>16);
        r.v[4]=bf2f(u.z&0xffff); r.v[5]=bf2f(u.z>>16);
        r.v[6]=bf2f(u.w&0xffff); r.v[7]=bf2f(u.w>>16);
    } else {
        const float* q = (const float*)p + i;
        float4 a = *(const float4*)q, b = *(const float4*)(q+4);
        r.v[0]=a.x; r.v[1]=a.y; r.v[2]=a.z; r.v[3]=a.w;
        r.v[4]=b.x; r.v[5]=b.y; r.v[6]=b.z; r.v[7]=b.w;
    }
    return r;
}

__device__ __forceinline__ float wave_sum(float v) {
    #pragma unroll
    for (int m = 1; m < 64; m <<= 1) v += __shfl_xor(v, m, 64);
    return v;
}
__device__ __forceinline__ float wave_max(float v) {
    #pragma unroll
    for (int m = 1; m < 64; m <<= 1) v = fmaxf(v, __shfl_xor(v, m, 64));
    return v;
}
__device__ __forceinline__ float blk_sum(float v, float* sh) {
    v = wave_sum(v);
    int w = threadIdx.x >> 6, nw = blockDim.x >> 6;
    if ((threadIdx.x & 63) == 0) sh[w] = v;
    __syncthreads();
    float s = sh[0];
    for (int i = 1; i < nw; ++i) s += sh[i];
    __syncthreads();
    return s;
}
__device__ __forceinline__ float blk_max(float v, float* sh) {
    v = wave_max(v);
    int w = threadIdx.x >> 6, nw = blockDim.x >> 6;
    if ((threadIdx.x & 63) == 0) sh[w] = v;
    __syncthreads();
    float s = sh[0];
    for (int i = 1; i < nw; ++i) s = fmaxf(s, sh[i]);
    __syncthreads();
    return s;
}

// ---- fused prep: LN0(h_V)->x0 bf16  |  3 weight transposes  |  zero stats/accum ----
// grid = 8192 (rows) + 64 (wt1) + 16 (wt2) + 4 (wt3) + 32 (zeros) = 8308
__global__ __launch_bounds__(256) void prep_k(const void* __restrict__ hv,
        const void* __restrict__ g0, const void* __restrict__ b0, u16* __restrict__ x0,
        const void* __restrict__ w_in, u16* __restrict__ wt1,
        const void* __restrict__ w_h,  u16* __restrict__ wt2,
        const void* __restrict__ aw1,  u16* __restrict__ wt3,
        float* __restrict__ zA, float* __restrict__ zB,
        const u32* __restrict__ probe) {
    __shared__ u16 tile[64][65];
    __shared__ float sh[4];
    bool bf = (probe[0] == BF16_ONES_PAIR);
    int blk = blockIdx.x, t = threadIdx.x;
    if (blk < M_) {                        // LN0 one row
        float4 v = ld4(hv, (size_t)blk * F_ + t * 4, bf);
        float s = v.x + v.y + v.z + v.w;
        float q = v.x*v.x + v.y*v.y + v.z*v.z + v.w*v.w;
        s = blk_sum(s, sh);
        q = blk_sum(q, sh);
        float mean = s * (1.f / F_);
        float rstd = rsqrtf(q * (1.f / F_) - mean * mean + 1e-6f);
        float4 gg = ld4(g0, t * 4, bf);
        float4 bb = ld4(b0, t * 4, bf);
        u32 o0 = f2bf((v.x - mean) * rstd * gg.x + bb.x)
               | ((u32)f2bf((v.y - mean) * rstd * gg.y + bb.y) << 16);
        u32 o1 = f2bf((v.z - mean) * rstd * gg.z + bb.z)
               | ((u32)f2bf((v.w - mean) * rstd * gg.w + bb.w) << 16);
        *(uint2*)(x0 + (size_t)blk * F_ + t * 4) = make_uint2(o0, o1);
        return;
    }
    blk -= M_;
    const void* W = nullptr; u16* WT = nullptr; int K = 0, N = 0, kt = 0, nt = 0;
    if (blk < 64)      { W = w_in; WT = wt1; K = F_; N = H_; kt = blk & 15; nt = blk >> 4; }
    else if (blk < 80) { int j = blk - 64; W = w_h; WT = wt2; K = H_; N = H_; kt = j & 3; nt = j >> 2; }
    else if (blk < 84) { int j = blk - 80; W = aw1; WT = wt3; K = H_; N = 64; kt = j; nt = 0; }
    else {
        int j = blk - 84;
        if (j < 16) {                      // zero st1+st2 (32768 floats = 8192 f4)
            float4* p = (float4*)zA;
            for (int i = j * 256 + t; i < 8192; i += 4096) p[i] = make_float4(0,0,0,0);
        } else {                           // zero ha+l2 (54512 floats = 13628 f4)
            j -= 16;
            float4* p = (float4*)zB;
            for (int i = j * 256 + t; i < 13628; i += 4096) p[i] = make_float4(0,0,0,0);
        }
        return;
    }
    int kt0 = kt * 64, nt0 = nt * 64;
    int r = t >> 2, cq = (t & 3) * 16;
    #pragma unroll
    for (int j = 0; j < 4; ++j) {
        float4 v = ld4(W, (size_t)(kt0 + r) * N + nt0 + cq + j * 4, bf);
        tile[r][cq + j*4 + 0] = f2bf(v.x);
        tile[r][cq + j*4 + 1] = f2bf(v.y);
        tile[r][cq + j*4 + 2] = f2bf(v.z);
        tile[r][cq + j*4 + 3] = f2bf(v.w);
    }
    __syncthreads();
    #pragma unroll
    for (int j = 0; j < 4; ++j) {
        int k = cq + j * 4;
        u32 a0 = tile[k+0][r], a1 = tile[k+1][r], a2 = tile[k+2][r], a3 = tile[k+3][r];
        uint2 o; o.x = a0 | (a1 << 16); o.y = a2 | (a3 << 16);
        *(uint2*)(WT + (size_t)(nt0 + r) * K + kt0 + k) = o;
    }
}

// ---- MFMA bf16 GEMM: C = leaky([LN](A) @ W + bias); optional raw-stats epilogue ----
// amode: 1 = bf16 A + fused LN from raw sums statin; 2 = bf16 A plain.
// statout (nullable): per-row partial (sum, sumsq) of output via atomics.
__global__ __launch_bounds__(256) void gemm_mfma(const u16* __restrict__ Ap, int amode,
        const float2* __restrict__ statin, const void* __restrict__ g,
        const void* __restrict__ bta, const u16* __restrict__ WT,
        const void* __restrict__ bias, u16* __restrict__ C,
        float* __restrict__ statout, int M, int N, int K,
        const u32* __restrict__ probe) {
    __shared__ short8 As[64][5];
    __shared__ short8 Bs[64][5];
    bool pbf = (probe[0] == BF16_ONES_PAIR);
    int t = threadIdx.x;
    int m0 = blockIdx.x * 64, n0 = blockIdx.y * 64;
    int r = t >> 2, kq = t & 3;
    int l = t & 63, w = t >> 6;
    int q = l >> 4, ml = l & 15;
    float4v acc[4];
    #pragma unroll
    for (int nt = 0; nt < 4; ++nt)
        #pragma unroll
        for (int i = 0; i < 4; ++i) acc[nt][i] = 0.f;
    float stm = 0.f, str = 1.f;
    if (amode == 1) {
        float2 st = statin[m0 + r];
        float mm = st.x * (1.f / K);
        stm = mm;
        str = rsqrtf(st.y * (1.f / K) - mm * mm + 1e-6f);
    }
    for (int k0 = 0; k0 < K; k0 += 32) {
        int kk = k0 + kq * 8;
        short8 pa;
        if (amode == 1) {
            f8 a  = ld8(Ap, (size_t)(m0 + r) * K + kk, true);
            f8 gg = ld8(g, kk, pbf);
            f8 bb = ld8(bta, kk, pbf);
            #pragma unroll
            for (int j = 0; j < 8; ++j)
                pa[j] = (short)f2bf((a.v[j] - stm) * str * gg.v[j] + bb.v[j]);
        } else {
            pa = *(const short8*)(Ap + (size_t)(m0 + r) * K + kk);
        }
        short8 pb = *(const short8*)(WT + (size_t)(n0 + r) * K + kk);
        __syncthreads();
        As[r][kq] = pa;
        Bs[r][kq] = pb;
        __syncthreads();
        short8 af = As[w * 16 + ml][q];
        #pragma unroll
        for (int nt = 0; nt < 4; ++nt)
            acc[nt] = __builtin_amdgcn_mfma_f32_16x16x32_bf16(af, Bs[nt*16 + ml][q],
                                                              acc[nt], 0, 0, 0);
    }
    float ov[4][4];
    #pragma unroll
    for (int nt = 0; nt < 4; ++nt) {
        int nn = n0 + nt * 16 + ml;
        float bv = ldS(bias, nn, pbf);
        #pragma unroll
        for (int reg = 0; reg < 4; ++reg) {
            float v = acc[nt][reg] + bv;
            v = v >= 0.f ? v : 0.01f * v;
            ov[nt][reg] = v;
            C[(size_t)(m0 + w * 16 + q * 4 + reg) * N + nn] = f2bf(v);
        }
    }
    if (statout) {
        #pragma unroll
        for (int reg = 0; reg < 4; ++reg) {
            float sv = ov[0][reg] + ov[1][reg] + ov[2][reg] + ov[3][reg];
            float qv = ov[0][reg]*ov[0][reg] + ov[1][reg]*ov[1][reg]
                     + ov[2][reg]*ov[2][reg] + ov[3][reg]*ov[3][reg];
            #pragma unroll
            for (int mk = 1; mk < 16; mk <<= 1) {
                sv += __shfl_xor(sv, mk, 64);
                qv += __shfl_xor(qv, mk, 64);
            }
            if (ml == 0) {
                int row = m0 + w * 16 + q * 4 + reg;
                atomicAdd(&statout[2 * row],     sv);
                atomicAdd(&statout[2 * row + 1], qv);
            }
        }
    }
}

// ---- fused LN(64) + attn logits: one wave per row ----
__global__ __launch_bounds__(256) void attnlog_k(const u16* __restrict__ abr,
        const void* __restrict__ g, const void* __restrict__ b,
        const void* __restrict__ w2, const void* __restrict__ b2,
        const int* __restrict__ mask, float* __restrict__ lg,
        const u32* __restrict__ probe) {
    __shared__ float w2s[512];
    __shared__ float b2s[8];
    bool pbf = (probe[0] == BF16_ONES_PAIR);
    int t = threadIdx.x;
    for (int i = t; i < 512; i += 256) w2s[i] = ldS(w2, i, pbf);
    if (t < 8) b2s[t] = ldS(b2, t, pbf);
    __syncthreads();
    int l = t & 63, w = t >> 6;
    int row = blockIdx.x * 4 + w;
    float a = bf2f(abr[(size_t)row * 64 + l]);
    float s = wave_sum(a);
    float q = wave_sum(a * a);
    float m = s * (1.f / 64), var = q * (1.f / 64) - m * m;
    float val = (a - m) * rsqrtf(var + 1e-6f) * ldS(g, l, pbf) + ldS(b, l, pbf);
    float mine = 0.f;
    #pragma unroll
    for (int h = 0; h < 8; ++h) {
        float sh_ = wave_sum(val * w2s[l * 8 + h]);
        if (l == h) mine = sh_;
    }
    if (l < 8) {
        int bb = row >> 10, ll = row & 1023;
        float v = mine + b2s[l];
        if (mask[row] == 0) v = -1e9f;
        lg[((size_t)bb * NH_ + l) * L_ + ll] = v;
    }
}

// ---- fused softmax + rstd-fold + pooling + LN2-affine: one block per (b,h) ----
__global__ __launch_bounds__(256) void softpool_k(const float* __restrict__ lg,
        const float2* __restrict__ st2, const u16* __restrict__ x2,
        const void* __restrict__ g, const void* __restrict__ b,
        float* __restrict__ hp, const u32* __restrict__ probe) {
    __shared__ float sh[4];
    __shared__ float awl[1024];
    bool pbf = (probe[0] == BF16_ONES_PAIR);
    int bh = blockIdx.x, t = threadIdx.x, bb = bh >> 3;
    size_t base = (size_t)bh * L_;
    float4 v = ((const float4*)(lg + base))[t];
    float mx = blk_max(fmaxf(fmaxf(v.x, v.y), fmaxf(v.z, v.w)), sh);
    v.x = expf(v.x - mx); v.y = expf(v.y - mx);
    v.z = expf(v.z - mx); v.w = expf(v.w - mx);
    float s = blk_sum(v.x + v.y + v.z + v.w, sh);
    float inv = 1.f / s;
    float va[4] = {v.x, v.y, v.z, v.w};
    float c1p = 0.f;
    #pragma unroll
    for (int j = 0; j < 4; ++j) {
        int idx = t * 4 + j;
        float2 st = st2[(bb << 10) + idx];
        float m = st.x * (1.f / 256);
        float r = rsqrtf(st.y * (1.f / 256) - m * m + 1e-6f);
        float aw = va[j] * inv * r;
        awl[idx] = aw;
        c1p += aw * m;
    }
    float c1 = blk_sum(c1p, sh);   // internal syncthreads orders awl writes
    const u16* xb = x2 + ((size_t)bb << 10) * 256;
    float S = 0.f;
    #pragma unroll 8
    for (int ll = 0; ll < 1024; ++ll)
        S += awl[ll] * bf2f(xb[(size_t)ll * 256 + t]);
    hp[(size_t)bh * 256 + t] = (S - c1) * ldS(g, t, pbf) + ldS(b, t, pbf);
}

// ---- split-K GEMV, 2 cols/thread, K-chunk 64 ----
__global__ __launch_bounds__(256) void gemv2_k(const float* __restrict__ hv,
        const void* __restrict__ W, float* __restrict__ acc, int K, int N,
        const u32* __restrict__ probe) {
    __shared__ float hs[8 * 64];
    bool bf = (probe[0] == BF16_ONES_PAIR);
    int t = threadIdx.x;
    int kb = blockIdx.y * 64;
    for (int i = t; i < 512; i += 256) {
        int r = i >> 6, k = i & 63;
        hs[i] = hv[(size_t)r * K + kb + k];
    }
    __syncthreads();
    int c0 = (blockIdx.x * 256 + t) * 2;
    if (c0 >= N) return;
    float a[8][2] = {};
    #pragma unroll 4
    for (int k = 0; k < 64; ++k) {
        float w0, w1;
        if (bf) {
            u32 u = *(const u32*)((const u16*)W + (size_t)(kb + k) * N + c0);
            w0 = bf2f(u & 0xffff); w1 = bf2f(u >> 16);
        } else {
            float2 fw = *(const float2*)((const float*)W + (size_t)(kb + k) * N + c0);
            w0 = fw.x; w1 = fw.y;
        }
        #pragma unroll
        for (int r = 0; r < 8; ++r) {
            float h = hs[(r << 6) + k];
            a[r][0] += h * w0; a[r][1] += h * w1;
        }
    }
    bool ok1 = (c0 + 1 < N);
    #pragma unroll
    for (int r = 0; r < 8; ++r) {
        atomicAdd(&acc[(size_t)r * N + c0], a[r][0]);
        if (ok1) atomicAdd(&acc[(size_t)r * N + c0 + 1], a[r][1]);
    }
}

// ---- bias + leaky + LN over 2048 cols, in place (8 rows) ----
__global__ __launch_bounds__(256) void out_ln_k(float* __restrict__ h,
        const void* __restrict__ bias, const void* __restrict__ g,
        const void* __restrict__ b, const u32* __restrict__ probe) {
    __shared__ float sh[4];
    bool bf = (probe[0] == BF16_ONES_PAIR);
    int row = blockIdx.x, t = threadIdx.x;
    float v[8];
    float s = 0.f, q = 0.f;
    #pragma unroll
    for (int i = 0; i < 8; ++i) {
        int c = t + i * 256;
        float x = h[(size_t)row * OD_ + c] + ldS(bias, c, bf);
        x = x >= 0.f ? x : 0.01f * x;
        v[i] = x; s += x; q += x * x;
    }
    s = blk_sum(s, sh) * (1.f / OD_);
    q = blk_sum(q, sh) * (1.f / OD_);
    float rstd = rsqrtf(q - s * s + 1e-6f);
    #pragma unroll
    for (int i = 0; i < 8; ++i) {
        int c = t + i * 256;
        h[(size_t)row * OD_ + c] = (v[i] - s) * rstd * ldS(g, c, bf) + ldS(b, c, bf);
    }
}

// ---- bias + sigmoid (transposed pt[c][r]) + zero d_out for maxprod ----
__global__ __launch_bounds__(256) void sigmoid_t_k(const float* __restrict__ acc,
        const void* __restrict__ bias, float* __restrict__ pt,
        float* __restrict__ out, const u32* __restrict__ probe) {
    bool bf = (probe[0] == BF16_ONES_PAIR);
    int c = blockIdx.x * 256 + threadIdx.x;
    if (c >= LBL_) return;
    float bv = ldS(bias, c, bf);
    float o[8];
    #pragma unroll
    for (int r = 0; r < 8; ++r) {
        float v = acc[(size_t)r * LBL_ + c] + bv;
        o[r] = 1.f / (1.f + expf(-v));
        out[(size_t)r * LBL_ + c] = 0.f;
    }
    float4* dst = (float4*)(pt + (size_t)c * 8);
    dst[0] = make_float4(o[0], o[1], o[2], o[3]);
    dst[1] = make_float4(o[4], o[5], o[6], o[7]);
}

// ---- per-nonzero hit: LDS max over 8 batches ----
__device__ __forceinline__ void mp_hit(u32 idx, float cmv,
        const float* __restrict__ pt, int* smax, u32 rowBase) {
    u32 i = idx / LBL_;
    u32 j = idx - i * LBL_;
    const float4* pj = (const float4*)(pt + (size_t)j * 8);
    float4 pa = pj[0], pb = pj[1];
    int base = (int)(i - rowBase) * 8;
    atomicMax(&smax[base + 0], __float_as_int(pa.x * cmv));
    atomicMax(&smax[base + 1], __float_as_int(pa.y * cmv));
    atomicMax(&smax[base + 2], __float_as_int(pa.z * cmv));
    atomicMax(&smax[base + 3], __float_as_int(pa.w * cmv));
    atomicMax(&smax[base + 4], __float_as_int(pb.x * cmv));
    atomicMax(&smax[base + 5], __float_as_int(pb.y * cmv));
    atomicMax(&smax[base + 6], __float_as_int(pb.z * cmv));
    atomicMax(&smax[base + 7], __float_as_int(pb.w * cmv));
}

// ---- GO max-product: block-owned CM ranges, LDS row-max, few global atomics ----
__global__ __launch_bounds__(256) void maxprod3_k(const float* __restrict__ pt,
        const void* __restrict__ CM, float* __restrict__ out,
        const u32* __restrict__ probe) {
    __shared__ int smax[6 * 8];
    bool bf = (probe[0] == BF16_ONES_PAIR);
    int t = threadIdx.x;
    size_t blockStart = (size_t)blockIdx.x * MP_EPB;
    u32 rowBase = (u32)(blockStart / LBL_);
    for (int i = t; i < 48; i += 256) smax[i] = 0;
    __syncthreads();
    if (bf) {
        const u16* cm = (const u16*)CM;
        uint4 ch[8];
        size_t i0[8];
        #pragma unroll
        for (int u = 0; u < 8; ++u) {
            size_t idx0 = blockStart + ((size_t)u * 256 + t) * 8;
            i0[u] = idx0;
            ch[u] = (idx0 + 8 <= NCM) ? *(const uint4*)(cm + idx0)
                                      : make_uint4(0, 0, 0, 0);
        }
        #pragma unroll
        for (int u = 0; u < 8; ++u) {
            size_t idx0 = i0[u];
            if (idx0 + 8 <= NCM) {
                uint4 c4 = ch[u];
                if ((c4.x | c4.y | c4.z | c4.w) == 0) continue;
                u32 hw[4] = {c4.x, c4.y, c4.z, c4.w};
                #pragma unroll
                for (int d = 0; d < 4; ++d) {
                    u32 lo = hw[d] & 0xffff, hi = hw[d] >> 16;
                    if (lo) mp_hit((u32)idx0 + d*2,     bf2f(lo), pt, smax, rowBase);
                    if (hi) mp_hit((u32)idx0 + d*2 + 1, bf2f(hi), pt, smax, rowBase);
                }
            } else if (idx0 < NCM) {
                for (u32 e = 0; e < (u32)(NCM - idx0); ++e) {
                    u16 h = cm[idx0 + e];
                    if (h) mp_hit((u32)idx0 + e, bf2f(h), pt, smax, rowBase);
                }
            }
        }
    } else {
        const float* cm = (const float*)CM;
        #pragma unroll
        for (int u = 0; u < 16; ++u) {
            size_t idx0 = blockStart + ((size_t)u * 256 + t) * 4;
            if (idx0 >= NCM) continue;
            float v[4];
            if (idx0 + 4 <= NCM) {
                float4 f = *(const float4*)(cm + idx0);
                v[0] = f.x; v[1] = f.y; v[2] = f.z; v[3] = f.w;
            } else {
                v[0] = v[1] = v[2] = v[3] = 0.f;
                for (u32 e = 0; e < (u32)(NCM - idx0); ++e) v[e] = cm[idx0 + e];
            }
            if (v[0] == 0.f && v[1] == 0.f && v[2] == 0.f && v[3] == 0.f) continue;
            #pragma unroll
            for (int e = 0; e < 4; ++e)
                if (v[e] != 0.f) mp_hit((u32)idx0 + e, v[e], pt, smax, rowBase);
        }
    }
    __syncthreads();
    size_t lastIdx = blockStart + MP_EPB - 1;
    if (lastIdx >= NCM) lastIdx = NCM - 1;
    int nrows = (int)((u32)(lastIdx / LBL_) - rowBase) + 1;
    for (int s = t; s < nrows * 8; s += 256) {
        int v = smax[s];
        if (v != 0) {
            int rr = s >> 3, b = s & 7;
            atomicMax((int*)(out + (size_t)b * LBL_ + rowBase + rr), v);
        }
    }
}

extern "C" void kernel_launch(void* const* d_in, const int* in_sizes, int n_in,
                              void* d_out, int out_size, void* d_ws, size_t ws_size,
                              hipStream_t stream) {
    const void* hv   = d_in[0];
    const int* mask  = (const int*)d_in[1];
    const void* ln0g = d_in[2];
    const void* ln0b = d_in[3];
    const void* w_in = d_in[4];
    const void* b_in = d_in[5];
    const void* ln1g = d_in[6];
    const void* ln1b = d_in[7];
    const void* w_h  = d_in[8];
    const void* b_h  = d_in[9];
    const void* ln2g = d_in[10];
    const void* ln2b = d_in[11];
    const void* aw1  = d_in[12];
    const void* ab1  = d_in[13];
    const void* alng = d_in[14];
    const void* alnb = d_in[15];
    const void* aw2  = d_in[16];
    const void* ab2  = d_in[17];
    const void* ow1  = d_in[18];
    const void* ob1  = d_in[19];
    const void* olng = d_in[20];
    const void* olnb = d_in[21];
    const void* ow2  = d_in[22];
    const void* ob2  = d_in[23];
    const void* CM   = d_in[24];
    const u32* probe = (const u32*)ln0g;
    float* out = (float*)d_out;

    float* f = (float*)d_ws;
    float2* st1 = (float2*)f;                    // f[0..16384)      raw (sum,sumsq) x1 rows
    float2* st2 = st1 + 8192;                    // f[16384..32768)  raw (sum,sumsq) x2 rows
    float* lg = f + 32768;                       // 65536  [8,8,1024]
    float* hp = lg + 65536;                      // 16384
    float* ha = hp + 16384;                      // 16384  (zeroed accum)
    float* l2 = ha + 16384;                      // 38128  (zeroed accum)
    float* pt = l2 + 38128;                      // 38128  (transposed sigmoid)
    u16* x0  = (u16*)(pt + 38128);               // 8192*1024
    u16* x1  = x0 + 8388608;                     // 8192*256
    u16* x2  = x1 + 2097152;                     // 8192*256
    u16* abr = x2 + 2097152;                     // 8192*64
    u16* wt1 = abr + 524288;                     // 256*1024
    u16* wt2 = wt1 + 262144;                     // 256*256
    u16* wt3 = wt2 + 65536;                      // 64*256

    // 1: LN0 + transposes + zero(st1,st2) + zero(ha,l2)
    prep_k<<<M_ + 84 + 32, 256, 0, stream>>>(hv, ln0g, ln0b, x0,
                                             w_in, wt1, w_h, wt2, aw1, wt3,
                                             f, ha, probe);
    // 2-4: trunk GEMMs (stats fused into epilogues)
    gemm_mfma<<<dim3(M_/64, 4), 256, 0, stream>>>(x0, 2, nullptr, nullptr, nullptr,
                                                  wt1, b_in, x1, (float*)st1,
                                                  M_, H_, F_, probe);
    gemm_mfma<<<dim3(M_/64, 4), 256, 0, stream>>>(x1, 1, st1, ln1g, ln1b,
                                                  wt2, b_h, x2, (float*)st2,
                                                  M_, H_, H_, probe);
    gemm_mfma<<<dim3(M_/64, 1), 256, 0, stream>>>(x2, 1, st2, ln2g, ln2b,
                                                  wt3, ab1, abr, nullptr,
                                                  M_, 64, H_, probe);
    // 5-6: attention
    attnlog_k<<<M_/4, 256, 0, stream>>>(abr, alng, alnb, aw2, ab2, mask, lg, probe);
    softpool_k<<<B_*NH_, 256, 0, stream>>>(lg, st2, x2, ln2g, ln2b, hp, probe);
    // 7-10: output block
    gemv2_k<<<dim3(OD_/512, 32), 256, 0, stream>>>(hp, ow1, ha, OD_, OD_, probe);
    out_ln_k<<<B_, 256, 0, stream>>>(ha, ob1, olng, olnb, probe);
    gemv2_k<<<dim3((LBL_+511)/512, 32), 256, 0, stream>>>(ha, ow2, l2, OD_, LBL_, probe);
    sigmoid_t_k<<<(LBL_+255)/256, 256, 0, stream>>>(l2, ob2, pt, out, probe);
    // 11: GO max-product
    maxprod3_k<<<MP_NB, 256, 0, stream>>>(pt, CM, out, probe);
}

// Round 10
// 358.526 us; speedup vs baseline: 1.0861x; 1.0861x over previous
//
#include <hip/hip_runtime.h>
#include <hip/hip_bf16.h>
#include <cstdint>

#define B_   8
#define L_   1024
#define F_   1024
#define H_   256
#define NH_  8
#define LBL_ 4766
#define M_   (B_*L_)    // 8192
#define OD_  (NH_*H_)   // 2048
#define NCM  (LBL_*LBL_)     // 22714756
#define MP_EPB 16384
#define MP_NB  ((NCM + MP_EPB - 1) / MP_EPB)   // 1387

typedef unsigned short u16;
typedef unsigned int   u32;
typedef __attribute__((ext_vector_type(8))) short short8;
typedef __attribute__((ext_vector_type(4))) float float4v;

#define BF16_ONES_PAIR 0x3f803f80u

__device__ __forceinline__ float bf2f(u32 u) { return __uint_as_float(u << 16); }
__device__ __forceinline__ u16 f2bf(float f) {
    u32 u = __float_as_uint(f);
    u32 r = 0x7fffu + ((u >> 16) & 1u);
    return (u16)((u + r) >> 16);
}

struct f8 { float v[8]; };

__device__ __forceinline__ float ldS(const void* p, size_t i, bool bf) {
    return bf ? bf2f(((const u16*)p)[i]) : ((const float*)p)[i];
}
__device__ __forceinline__ float4 ld4(const void* p, size_t i, bool bf) {
    if (bf) {
        uint2 u = *(const uint2*)((const u16*)p + i);
        return make_float4(bf2f(u.x & 0xffff), bf2f(u.x >> 16),
                           bf2f(u.y & 0xffff), bf2f(u.y >> 16));
    }
    return *(const float4*)((const float*)p + i);
}
__device__ __forceinline__ f8 ld8(const void* p, size_t i, bool bf) {
    f8 r;
    if (bf) {
        uint4 u = *(const uint4*)((const u16*)p + i);
        r.v[0]=bf2f(u.x&0xffff); r.v[1]=bf2f(u.x>>16);
        r.v[2]=bf2f(u.y&0xffff); r.v[3]=bf2f(u.y>>16);
        r.v[4]=bf2f(u.z&0xffff); r.v[5]=bf2f(u.z>>16);
        r.v[6]=bf2f(u.w&0xffff); r.v[7]=bf2f(u.w>>16);
    } else {
        const float* q = (const float*)p + i;
        float4 a = *(const float4*)q, b = *(const float4*)(q+4);
        r.v[0]=a.x; r.v[1]=a.y; r.v[2]=a.z; r.v[3]=a.w;
        r.v[4]=b.x; r.v[5]=b.y; r.v[6]=b.z; r.v[7]=b.w;
    }
    return r;
}

__device__ __forceinline__ float wave_sum(float v) {
    #pragma unroll
    for (int m = 1; m < 64; m <<= 1) v += __shfl_xor(v, m, 64);
    return v;
}
__device__ __forceinline__ float wave_max(float v) {
    #pragma unroll
    for (int m = 1; m < 64; m <<= 1) v = fmaxf(v, __shfl_xor(v, m, 64));
    return v;
}
__device__ __forceinline__ float blk_sum(float v, float* sh) {
    v = wave_sum(v);
    int w = threadIdx.x >> 6, nw = blockDim.x >> 6;
    if ((threadIdx.x & 63) == 0) sh[w] = v;
    __syncthreads();
    float s = sh[0];
    for (int i = 1; i < nw; ++i) s += sh[i];
    __syncthreads();
    return s;
}
__device__ __forceinline__ float blk_max(float v, float* sh) {
    v = wave_max(v);
    int w = threadIdx.x >> 6, nw = blockDim.x >> 6;
    if ((threadIdx.x & 63) == 0) sh[w] = v;
    __syncthreads();
    float s = sh[0];
    for (int i = 1; i < nw; ++i) s = fmaxf(s, sh[i]);
    __syncthreads();
    return s;
}

// ---- fused prep: LN0(h_V)->x0 bf16  |  3 weight transposes  |  zero stats/accum ----
__global__ __launch_bounds__(256) void prep_k(const void* __restrict__ hv,
        const void* __restrict__ g0, const void* __restrict__ b0, u16* __restrict__ x0,
        const void* __restrict__ w_in, u16* __restrict__ wt1,
        const void* __restrict__ w_h,  u16* __restrict__ wt2,
        const void* __restrict__ aw1,  u16* __restrict__ wt3,
        float* __restrict__ zA, float* __restrict__ zB,
        const u32* __restrict__ probe) {
    __shared__ u16 tile[64][65];
    __shared__ float sh[4];
    bool bf = (probe[0] == BF16_ONES_PAIR);
    int blk = blockIdx.x, t = threadIdx.x;
    if (blk < M_) {                        // LN0 one row
        float4 v = ld4(hv, (size_t)blk * F_ + t * 4, bf);
        float s = v.x + v.y + v.z + v.w;
        float q = v.x*v.x + v.y*v.y + v.z*v.z + v.w*v.w;
        s = blk_sum(s, sh);
        q = blk_sum(q, sh);
        float mean = s * (1.f / F_);
        float rstd = rsqrtf(q * (1.f / F_) - mean * mean + 1e-6f);
        float4 gg = ld4(g0, t * 4, bf);
        float4 bb = ld4(b0, t * 4, bf);
        u32 o0 = f2bf((v.x - mean) * rstd * gg.x + bb.x)
               | ((u32)f2bf((v.y - mean) * rstd * gg.y + bb.y) << 16);
        u32 o1 = f2bf((v.z - mean) * rstd * gg.z + bb.z)
               | ((u32)f2bf((v.w - mean) * rstd * gg.w + bb.w) << 16);
        *(uint2*)(x0 + (size_t)blk * F_ + t * 4) = make_uint2(o0, o1);
        return;
    }
    blk -= M_;
    const void* W = nullptr; u16* WT = nullptr; int K = 0, N = 0, kt = 0, nt = 0;
    if (blk < 64)      { W = w_in; WT = wt1; K = F_; N = H_; kt = blk & 15; nt = blk >> 4; }
    else if (blk < 80) { int j = blk - 64; W = w_h; WT = wt2; K = H_; N = H_; kt = j & 3; nt = j >> 2; }
    else if (blk < 84) { int j = blk - 80; W = aw1; WT = wt3; K = H_; N = 64; kt = j; nt = 0; }
    else {
        int j = blk - 84;
        if (j < 16) {                      // zero st1+st2 (32768 floats = 8192 f4)
            float4* p = (float4*)zA;
            for (int i = j * 256 + t; i < 8192; i += 4096) p[i] = make_float4(0,0,0,0);
        } else {                           // zero ha+l2 (54512 floats = 13628 f4)
            j -= 16;
            float4* p = (float4*)zB;
            for (int i = j * 256 + t; i < 13628; i += 4096) p[i] = make_float4(0,0,0,0);
        }
        return;
    }
    int kt0 = kt * 64, nt0 = nt * 64;
    int r = t >> 2, cq = (t & 3) * 16;
    #pragma unroll
    for (int j = 0; j < 4; ++j) {
        float4 v = ld4(W, (size_t)(kt0 + r) * N + nt0 + cq + j * 4, bf);
        tile[r][cq + j*4 + 0] = f2bf(v.x);
        tile[r][cq + j*4 + 1] = f2bf(v.y);
        tile[r][cq + j*4 + 2] = f2bf(v.z);
        tile[r][cq + j*4 + 3] = f2bf(v.w);
    }
    __syncthreads();
    #pragma unroll
    for (int j = 0; j < 4; ++j) {
        int k = cq + j * 4;
        u32 a0 = tile[k+0][r], a1 = tile[k+1][r], a2 = tile[k+2][r], a3 = tile[k+3][r];
        uint2 o; o.x = a0 | (a1 << 16); o.y = a2 | (a3 << 16);
        *(uint2*)(WT + (size_t)(nt0 + r) * K + kt0 + k) = o;
    }
}

// ---- MFMA bf16 GEMM: C = leaky([LN](A) @ W + bias); optional raw-stats epilogue ----
__global__ __launch_bounds__(256) void gemm_mfma(const u16* __restrict__ Ap, int amode,
        const float2* __restrict__ statin, const void* __restrict__ g,
        const void* __restrict__ bta, const u16* __restrict__ WT,
        const void* __restrict__ bias, u16* __restrict__ C,
        float* __restrict__ statout, int M, int N, int K,
        const u32* __restrict__ probe) {
    __shared__ short8 As[64][5];
    __shared__ short8 Bs[64][5];
    bool pbf = (probe[0] == BF16_ONES_PAIR);
    int t = threadIdx.x;
    int m0 = blockIdx.x * 64, n0 = blockIdx.y * 64;
    int r = t >> 2, kq = t & 3;
    int l = t & 63, w = t >> 6;
    int q = l >> 4, ml = l & 15;
    float4v acc[4];
    #pragma unroll
    for (int nt = 0; nt < 4; ++nt)
        #pragma unroll
        for (int i = 0; i < 4; ++i) acc[nt][i] = 0.f;
    float stm = 0.f, str = 1.f;
    if (amode == 1) {
        float2 st = statin[m0 + r];
        float mm = st.x * (1.f / K);
        stm = mm;
        str = rsqrtf(st.y * (1.f / K) - mm * mm + 1e-6f);
    }
    for (int k0 = 0; k0 < K; k0 += 32) {
        int kk = k0 + kq * 8;
        short8 pa;
        if (amode == 1) {
            f8 a  = ld8(Ap, (size_t)(m0 + r) * K + kk, true);
            f8 gg = ld8(g, kk, pbf);
            f8 bb = ld8(bta, kk, pbf);
            #pragma unroll
            for (int j = 0; j < 8; ++j)
                pa[j] = (short)f2bf((a.v[j] - stm) * str * gg.v[j] + bb.v[j]);
        } else {
            pa = *(const short8*)(Ap + (size_t)(m0 + r) * K + kk);
        }
        short8 pb = *(const short8*)(WT + (size_t)(n0 + r) * K + kk);
        __syncthreads();
        As[r][kq] = pa;
        Bs[r][kq] = pb;
        __syncthreads();
        short8 af = As[w * 16 + ml][q];
        #pragma unroll
        for (int nt = 0; nt < 4; ++nt)
            acc[nt] = __builtin_amdgcn_mfma_f32_16x16x32_bf16(af, Bs[nt*16 + ml][q],
                                                              acc[nt], 0, 0, 0);
    }
    float ov[4][4];
    #pragma unroll
    for (int nt = 0; nt < 4; ++nt) {
        int nn = n0 + nt * 16 + ml;
        float bv = ldS(bias, nn, pbf);
        #pragma unroll
        for (int reg = 0; reg < 4; ++reg) {
            float v = acc[nt][reg] + bv;
            v = v >= 0.f ? v : 0.01f * v;
            ov[nt][reg] = v;
            C[(size_t)(m0 + w * 16 + q * 4 + reg) * N + nn] = f2bf(v);
        }
    }
    if (statout) {
        #pragma unroll
        for (int reg = 0; reg < 4; ++reg) {
            float sv = ov[0][reg] + ov[1][reg] + ov[2][reg] + ov[3][reg];
            float qv = ov[0][reg]*ov[0][reg] + ov[1][reg]*ov[1][reg]
                     + ov[2][reg]*ov[2][reg] + ov[3][reg]*ov[3][reg];
            #pragma unroll
            for (int mk = 1; mk < 16; mk <<= 1) {
                sv += __shfl_xor(sv, mk, 64);
                qv += __shfl_xor(qv, mk, 64);
            }
            if (ml == 0) {
                int row = m0 + w * 16 + q * 4 + reg;
                atomicAdd(&statout[2 * row],     sv);
                atomicAdd(&statout[2 * row + 1], qv);
            }
        }
    }
}

// ---- fused LN(64) + attn logits: one wave per row ----
__global__ __launch_bounds__(256) void attnlog_k(const u16* __restrict__ abr,
        const void* __restrict__ g, const void* __restrict__ b,
        const void* __restrict__ w2, const void* __restrict__ b2,
        const int* __restrict__ mask, float* __restrict__ lg,
        const u32* __restrict__ probe) {
    __shared__ float w2s[512];
    __shared__ float b2s[8];
    bool pbf = (probe[0] == BF16_ONES_PAIR);
    int t = threadIdx.x;
    for (int i = t; i < 512; i += 256) w2s[i] = ldS(w2, i, pbf);
    if (t < 8) b2s[t] = ldS(b2, t, pbf);
    __syncthreads();
    int l = t & 63, w = t >> 6;
    int row = blockIdx.x * 4 + w;
    float a = bf2f(abr[(size_t)row * 64 + l]);
    float s = wave_sum(a);
    float q = wave_sum(a * a);
    float m = s * (1.f / 64), var = q * (1.f / 64) - m * m;
    float val = (a - m) * rsqrtf(var + 1e-6f) * ldS(g, l, pbf) + ldS(b, l, pbf);
    float mine = 0.f;
    #pragma unroll
    for (int h = 0; h < 8; ++h) {
        float sh_ = wave_sum(val * w2s[l * 8 + h]);
        if (l == h) mine = sh_;
    }
    if (l < 8) {
        int bb = row >> 10, ll = row & 1023;
        float v = mine + b2s[l];
        if (mask[row] == 0) v = -1e9f;
        lg[((size_t)bb * NH_ + l) * L_ + ll] = v;
    }
}

// ---- softmax over L + fold ln2 rstd (from raw sums) into weights; c1 side-sum ----
__global__ __launch_bounds__(256) void softmax2_k(float* __restrict__ lg,
        const float2* __restrict__ st2, float* __restrict__ c1) {
    __shared__ float sh[4];
    int bh = blockIdx.x, t = threadIdx.x;
    int b = bh >> 3;
    size_t base = (size_t)bh * L_;
    float4 v = ((float4*)(lg + base))[t];
    float mx = blk_max(fmaxf(fmaxf(v.x, v.y), fmaxf(v.z, v.w)), sh);
    v.x = expf(v.x - mx); v.y = expf(v.y - mx);
    v.z = expf(v.z - mx); v.w = expf(v.w - mx);
    float s = blk_sum(v.x + v.y + v.z + v.w, sh);
    float inv = 1.f / s;
    float va[4] = {v.x, v.y, v.z, v.w};
    float ao[4];
    float c1p = 0.f;
    #pragma unroll
    for (int j = 0; j < 4; ++j) {
        int idx = t * 4 + j;
        float2 st = st2[(b << 10) + idx];
        float m = st.x * (1.f / 256);
        float r = rsqrtf(st.y * (1.f / 256) - m * m + 1e-6f);
        float aw = va[j] * inv * r;
        ao[j] = aw;
        c1p += aw * m;
    }
    ((float4*)(lg + base))[t] = make_float4(ao[0], ao[1], ao[2], ao[3]);
    float c = blk_sum(c1p, sh);
    if (t == 0) c1[bh] = c;
}

// ---- pooling partials over 8 L-chunks: Sp[c][bh][d] (512 blocks) ----
__global__ __launch_bounds__(256) void pool_part8_k(const float* __restrict__ lg,
        const u16* __restrict__ x2, float* __restrict__ Sp) {
    int bh = blockIdx.x, c = blockIdx.y, t = threadIdx.x;
    int b = bh >> 3, l0 = c << 7;
    const float* aw = lg + (size_t)bh * L_ + l0;
    const u16* xb = x2 + ((size_t)(b << 10) + l0) * 256;
    float acc = 0.f;
    #pragma unroll 8
    for (int i = 0; i < 128; ++i)
        acc += aw[i] * bf2f(xb[(size_t)i * 256 + t]);
    Sp[((size_t)c * 64 + bh) * 256 + t] = acc;
}

// ---- combine pooling + LN2-affine ----
__global__ __launch_bounds__(256) void pool_comb8_k(const float* __restrict__ Sp,
        const float* __restrict__ c1, const void* __restrict__ g,
        const void* __restrict__ b, float* __restrict__ hp,
        const u32* __restrict__ probe) {
    bool pbf = (probe[0] == BF16_ONES_PAIR);
    int bh = blockIdx.x, t = threadIdx.x;
    float S = 0.f;
    #pragma unroll
    for (int c = 0; c < 8; ++c)
        S += Sp[((size_t)c * 64 + bh) * 256 + t];
    hp[(size_t)bh * 256 + t] = (S - c1[bh]) * ldS(g, t, pbf) + ldS(b, t, pbf);
}

// ---- split-K GEMV, 2 cols/thread, K-chunk 64 ----
__global__ __launch_bounds__(256) void gemv2_k(const float* __restrict__ hv,
        const void* __restrict__ W, float* __restrict__ acc, int K, int N,
        const u32* __restrict__ probe) {
    __shared__ float hs[8 * 64];
    bool bf = (probe[0] == BF16_ONES_PAIR);
    int t = threadIdx.x;
    int kb = blockIdx.y * 64;
    for (int i = t; i < 512; i += 256) {
        int r = i >> 6, k = i & 63;
        hs[i] = hv[(size_t)r * K + kb + k];
    }
    __syncthreads();
    int c0 = (blockIdx.x * 256 + t) * 2;
    if (c0 >= N) return;
    float a[8][2] = {};
    #pragma unroll 4
    for (int k = 0; k < 64; ++k) {
        float w0, w1;
        if (bf) {
            u32 u = *(const u32*)((const u16*)W + (size_t)(kb + k) * N + c0);
            w0 = bf2f(u & 0xffff); w1 = bf2f(u >> 16);
        } else {
            float2 fw = *(const float2*)((const float*)W + (size_t)(kb + k) * N + c0);
            w0 = fw.x; w1 = fw.y;
        }
        #pragma unroll
        for (int r = 0; r < 8; ++r) {
            float h = hs[(r << 6) + k];
            a[r][0] += h * w0; a[r][1] += h * w1;
        }
    }
    bool ok1 = (c0 + 1 < N);
    #pragma unroll
    for (int r = 0; r < 8; ++r) {
        atomicAdd(&acc[(size_t)r * N + c0], a[r][0]);
        if (ok1) atomicAdd(&acc[(size_t)r * N + c0 + 1], a[r][1]);
    }
}

// ---- bias + leaky + LN over 2048 cols, in place (8 rows) ----
__global__ __launch_bounds__(256) void out_ln_k(float* __restrict__ h,
        const void* __restrict__ bias, const void* __restrict__ g,
        const void* __restrict__ b, const u32* __restrict__ probe) {
    __shared__ float sh[4];
    bool bf = (probe[0] == BF16_ONES_PAIR);
    int row = blockIdx.x, t = threadIdx.x;
    float v[8];
    float s = 0.f, q = 0.f;
    #pragma unroll
    for (int i = 0; i < 8; ++i) {
        int c = t + i * 256;
        float x = h[(size_t)row * OD_ + c] + ldS(bias, c, bf);
        x = x >= 0.f ? x : 0.01f * x;
        v[i] = x; s += x; q += x * x;
    }
    s = blk_sum(s, sh) * (1.f / OD_);
    q = blk_sum(q, sh) * (1.f / OD_);
    float rstd = rsqrtf(q - s * s + 1e-6f);
    #pragma unroll
    for (int i = 0; i < 8; ++i) {
        int c = t + i * 256;
        h[(size_t)row * OD_ + c] = (v[i] - s) * rstd * ldS(g, c, bf) + ldS(b, c, bf);
    }
}

// ---- bias + sigmoid (transposed pt[c][r]) + zero d_out for maxprod ----
__global__ __launch_bounds__(256) void sigmoid_t_k(const float* __restrict__ acc,
        const void* __restrict__ bias, float* __restrict__ pt,
        float* __restrict__ out, const u32* __restrict__ probe) {
    bool bf = (probe[0] == BF16_ONES_PAIR);
    int c = blockIdx.x * 256 + threadIdx.x;
    if (c >= LBL_) return;
    float bv = ldS(bias, c, bf);
    float o[8];
    #pragma unroll
    for (int r = 0; r < 8; ++r) {
        float v = acc[(size_t)r * LBL_ + c] + bv;
        o[r] = 1.f / (1.f + expf(-v));
        out[(size_t)r * LBL_ + c] = 0.f;
    }
    float4* dst = (float4*)(pt + (size_t)c * 8);
    dst[0] = make_float4(o[0], o[1], o[2], o[3]);
    dst[1] = make_float4(o[4], o[5], o[6], o[7]);
}

// ---- per-nonzero hit: LDS max over 8 batches ----
__device__ __forceinline__ void mp_hit(u32 idx, float cmv,
        const float* __restrict__ pt, int* smax, u32 rowBase) {
    u32 i = idx / LBL_;
    u32 j = idx - i * LBL_;
    const float4* pj = (const float4*)(pt + (size_t)j * 8);
    float4 pa = pj[0], pb = pj[1];
    int base = (int)(i - rowBase) * 8;
    atomicMax(&smax[base + 0], __float_as_int(pa.x * cmv));
    atomicMax(&smax[base + 1], __float_as_int(pa.y * cmv));
    atomicMax(&smax[base + 2], __float_as_int(pa.z * cmv));
    atomicMax(&smax[base + 3], __float_as_int(pa.w * cmv));
    atomicMax(&smax[base + 4], __float_as_int(pb.x * cmv));
    atomicMax(&smax[base + 5], __float_as_int(pb.y * cmv));
    atomicMax(&smax[base + 6], __float_as_int(pb.z * cmv));
    atomicMax(&smax[base + 7], __float_as_int(pb.w * cmv));
}

// ---- GO max-product: block-owned CM ranges, LDS row-max, few global atomics ----
__global__ __launch_bounds__(256) void maxprod3_k(const float* __restrict__ pt,
        const void* __restrict__ CM, float* __restrict__ out,
        const u32* __restrict__ probe) {
    __shared__ int smax[6 * 8];
    bool bf = (probe[0] == BF16_ONES_PAIR);
    int t = threadIdx.x;
    size_t blockStart = (size_t)blockIdx.x * MP_EPB;
    u32 rowBase = (u32)(blockStart / LBL_);
    for (int i = t; i < 48; i += 256) smax[i] = 0;
    __syncthreads();
    if (bf) {
        const u16* cm = (const u16*)CM;
        uint4 ch[8];
        size_t i0[8];
        #pragma unroll
        for (int u = 0; u < 8; ++u) {
            size_t idx0 = blockStart + ((size_t)u * 256 + t) * 8;
            i0[u] = idx0;
            ch[u] = (idx0 + 8 <= NCM) ? *(const uint4*)(cm + idx0)
                                      : make_uint4(0, 0, 0, 0);
        }
        #pragma unroll
        for (int u = 0; u < 8; ++u) {
            size_t idx0 = i0[u];
            if (idx0 + 8 <= NCM) {
                uint4 c4 = ch[u];
                if ((c4.x | c4.y | c4.z | c4.w) == 0) continue;
                u32 hw[4] = {c4.x, c4.y, c4.z, c4.w};
                #pragma unroll
                for (int d = 0; d < 4; ++d) {
                    u32 lo = hw[d] & 0xffff, hi = hw[d] >> 16;
                    if (lo) mp_hit((u32)idx0 + d*2,     bf2f(lo), pt, smax, rowBase);
                    if (hi) mp_hit((u32)idx0 + d*2 + 1, bf2f(hi), pt, smax, rowBase);
                }
            } else if (idx0 < NCM) {
                for (u32 e = 0; e < (u32)(NCM - idx0); ++e) {
                    u16 h = cm[idx0 + e];
                    if (h) mp_hit((u32)idx0 + e, bf2f(h), pt, smax, rowBase);
                }
            }
        }
    } else {
        const float* cm = (const float*)CM;
        #pragma unroll
        for (int u = 0; u < 16; ++u) {
            size_t idx0 = blockStart + ((size_t)u * 256 + t) * 4;
            if (idx0 >= NCM) continue;
            float v[4];
            if (idx0 + 4 <= NCM) {
                float4 f = *(const float4*)(cm + idx0);
                v[0] = f.x; v[1] = f.y; v[2] = f.z; v[3] = f.w;
            } else {
                v[0] = v[1] = v[2] = v[3] = 0.f;
                for (u32 e = 0; e < (u32)(NCM - idx0); ++e) v[e] = cm[idx0 + e];
            }
            if (v[0] == 0.f && v[1] == 0.f && v[2] == 0.f && v[3] == 0.f) continue;
            #pragma unroll
            for (int e = 0; e < 4; ++e)
                if (v[e] != 0.f) mp_hit((u32)idx0 + e, v[e], pt, smax, rowBase);
        }
    }
    __syncthreads();
    size_t lastIdx = blockStart + MP_EPB - 1;
    if (lastIdx >= NCM) lastIdx = NCM - 1;
    int nrows = (int)((u32)(lastIdx / LBL_) - rowBase) + 1;
    for (int s = t; s < nrows * 8; s += 256) {
        int v = smax[s];
        if (v != 0) {
            int rr = s >> 3, b = s & 7;
            atomicMax((int*)(out + (size_t)b * LBL_ + rowBase + rr), v);
        }
    }
}

extern "C" void kernel_launch(void* const* d_in, const int* in_sizes, int n_in,
                              void* d_out, int out_size, void* d_ws, size_t ws_size,
                              hipStream_t stream) {
    const void* hv   = d_in[0];
    const int* mask  = (const int*)d_in[1];
    const void* ln0g = d_in[2];
    const void* ln0b = d_in[3];
    const void* w_in = d_in[4];
    const void* b_in = d_in[5];
    const void* ln1g = d_in[6];
    const void* ln1b = d_in[7];
    const void* w_h  = d_in[8];
    const void* b_h  = d_in[9];
    const void* ln2g = d_in[10];
    const void* ln2b = d_in[11];
    const void* aw1  = d_in[12];
    const void* ab1  = d_in[13];
    const void* alng = d_in[14];
    const void* alnb = d_in[15];
    const void* aw2  = d_in[16];
    const void* ab2  = d_in[17];
    const void* ow1  = d_in[18];
    const void* ob1  = d_in[19];
    const void* olng = d_in[20];
    const void* olnb = d_in[21];
    const void* ow2  = d_in[22];
    const void* ob2  = d_in[23];
    const void* CM   = d_in[24];
    const u32* probe = (const u32*)ln0g;
    float* out = (float*)d_out;

    float* f = (float*)d_ws;
    float2* st1 = (float2*)f;                    // raw (sum,sumsq) x1 rows
    float2* st2 = st1 + 8192;                    // raw (sum,sumsq) x2 rows
    float* lg = f + 32768;                       // 65536  [8,8,1024]
    float* c1 = lg + 65536;                      // 64
    float* Sp = c1 + 64;                         // 8*64*256 = 131072
    float* hp = Sp + 131072;                     // 16384
    float* ha = hp + 16384;                      // 16384  (zeroed accum)
    float* l2 = ha + 16384;                      // 38128  (zeroed accum)
    float* pt = l2 + 38128;                      // 38128  (transposed sigmoid)
    u16* x0  = (u16*)(pt + 38128);               // 8192*1024
    u16* x1  = x0 + 8388608;                     // 8192*256
    u16* x2  = x1 + 2097152;                     // 8192*256
    u16* abr = x2 + 2097152;                     // 8192*64
    u16* wt1 = abr + 524288;                     // 256*1024
    u16* wt2 = wt1 + 262144;                     // 256*256
    u16* wt3 = wt2 + 65536;                      // 64*256

    // 1: LN0 + transposes + zero(st1,st2) + zero(ha,l2)
    prep_k<<<M_ + 84 + 32, 256, 0, stream>>>(hv, ln0g, ln0b, x0,
                                             w_in, wt1, w_h, wt2, aw1, wt3,
                                             f, ha, probe);
    // 2-4: trunk GEMMs (stats fused into epilogues)
    gemm_mfma<<<dim3(M_/64, 4), 256, 0, stream>>>(x0, 2, nullptr, nullptr, nullptr,
                                                  wt1, b_in, x1, (float*)st1,
                                                  M_, H_, F_, probe);
    gemm_mfma<<<dim3(M_/64, 4), 256, 0, stream>>>(x1, 1, st1, ln1g, ln1b,
                                                  wt2, b_h, x2, (float*)st2,
                                                  M_, H_, H_, probe);
    gemm_mfma<<<dim3(M_/64, 1), 256, 0, stream>>>(x2, 1, st2, ln2g, ln2b,
                                                  wt3, ab1, abr, nullptr,
                                                  M_, 64, H_, probe);
    // 5-8: attention (parallel split pooling)
    attnlog_k<<<M_/4, 256, 0, stream>>>(abr, alng, alnb, aw2, ab2, mask, lg, probe);
    softmax2_k<<<B_*NH_, 256, 0, stream>>>(lg, st2, c1);
    pool_part8_k<<<dim3(B_*NH_, 8), 256, 0, stream>>>(lg, x2, Sp);
    pool_comb8_k<<<B_*NH_, 256, 0, stream>>>(Sp, c1, ln2g, ln2b, hp, probe);
    // 9-12: output block
    gemv2_k<<<dim3(OD_/512, 32), 256, 0, stream>>>(hp, ow1, ha, OD_, OD_, probe);
    out_ln_k<<<B_, 256, 0, stream>>>(ha, ob1, olng, olnb, probe);
    gemv2_k<<<dim3((LBL_+511)/512, 32), 256, 0, stream>>>(ha, ow2, l2, OD_, LBL_, probe);
    sigmoid_t_k<<<(LBL_+255)/256, 256, 0, stream>>>(l2, ob2, pt, out, probe);
    // 13: GO max-product
    maxprod3_k<<<MP_NB, 256, 0, stream>>>(pt, CM, out, probe);
}